// Round 10
// baseline (233.090 us; speedup 1.0000x reference)
//
#include <hip/hip_runtime.h>
#include <hip/hip_bf16.h>
#include <math.h>

// Problem constants
#define V_ 5
#define B_ 2
#define C_ 32
#define D_ 48
#define H_ 128
#define W_ 160
#define NSRC 4
#define HW_ (H_ * W_)
#define DHW_ ((size_t)D_ * H_ * W_)
#define BHW_ (B_ * H_ * W_)             // 40960
#define TOTAL_BDHW (B_ * D_ * H_ * W_)  // 1966080

// vol grid: block = 256 thr covers 16w x 4h pixels x all 32 ch at one d.
// d innermost, then wg, h4, b; XCD-chunked.
#define NB_VOL (B_ * (H_ / 4) * (W_ / 16) * D_)  // 30720
#define NB_VOL8 (NB_VOL / 8)                     // 3840

// LDS box staging capacity (records): 20 cols x 8 rows x 64B = 10240 B/view.
#define CAPX 20
#define CAPY 8
#define BOXB (CAPX * CAPY * 64)   // 10240

typedef __attribute__((ext_vector_type(2))) float f32x2;

// ---------------------------------------------------------------------------
// K0: projection setup (8 threads, f64 internally).
// ---------------------------------------------------------------------------
__device__ __forceinline__ void combined_proj(const float* p, double* P) {
    double E[16], K[16];
    for (int i = 0; i < 16; ++i) { E[i] = (double)p[i]; K[i] = (double)p[16 + i]; }
    for (int i = 0; i < 16; ++i) P[i] = E[i];
    for (int r = 0; r < 3; ++r)
        for (int c = 0; c < 4; ++c) {
            double s = 0.0;
            for (int j = 0; j < 3; ++j) s += K[r * 4 + j] * E[j * 4 + c];
            P[r * 4 + c] = s;
        }
}

__device__ void invert4(const double* A, double* out) {
    double M[4][8];
    for (int r = 0; r < 4; ++r)
        for (int c = 0; c < 4; ++c) {
            M[r][c] = A[r * 4 + c];
            M[r][c + 4] = (r == c) ? 1.0 : 0.0;
        }
    for (int col = 0; col < 4; ++col) {
        int piv = col;
        double best = fabs(M[col][col]);
        for (int r = col + 1; r < 4; ++r) {
            double v = fabs(M[r][col]);
            if (v > best) { best = v; piv = r; }
        }
        if (piv != col)
            for (int c = 0; c < 8; ++c) {
                double t = M[col][c]; M[col][c] = M[piv][c]; M[piv][c] = t;
            }
        double s = 1.0 / M[col][col];
        for (int c = 0; c < 8; ++c) M[col][c] *= s;
        for (int r = 0; r < 4; ++r)
            if (r != col) {
                double f = M[r][col];
                if (f != 0.0)
                    for (int c = 0; c < 8; ++c) M[r][c] -= f * M[col][c];
            }
    }
    for (int r = 0; r < 4; ++r)
        for (int c = 0; c < 4; ++c) out[r * 4 + c] = M[r][c + 4];
}

__global__ void proj_kernel(const float* __restrict__ pm, float* __restrict__ out) {
    int t = threadIdx.x;
    if (t >= B_ * NSRC) return;
    int b = t / NSRC, i = t % NSRC;
    double Pref[16], Psrc[16];
    combined_proj(pm + (size_t)((b * V_ + 0) * 2) * 16, Pref);
    combined_proj(pm + (size_t)((b * V_ + (i + 1)) * 2) * 16, Psrc);
    double inv[16];
    invert4(Pref, inv);
    double M[16];
    for (int r = 0; r < 4; ++r)
        for (int c = 0; c < 4; ++c) {
            double s = 0.0;
            for (int j = 0; j < 4; ++j) s += Psrc[r * 4 + j] * inv[j * 4 + c];
            M[r * 4 + c] = s;
        }
    float* o = out + t * 12;
    o[0] = (float)M[0];  o[1] = (float)M[1];  o[2] = (float)M[2];
    o[3] = (float)M[4];  o[4] = (float)M[5];  o[5] = (float)M[6];
    o[6] = (float)M[8];  o[7] = (float)M[9];  o[8] = (float)M[10];
    o[9] = (float)M[3];  o[10] = (float)M[7]; o[11] = (float)M[11];
}

// ---------------------------------------------------------------------------
// K1: transpose + convert src views -> channel-last bf16 (i, b, h, w, c).
// ---------------------------------------------------------------------------
__global__ __launch_bounds__(256) void transpose_bf16_kernel(
    const float* __restrict__ in, __hip_bfloat16* __restrict__ outT) {
    __shared__ float tile[32][33];
    int ibh = blockIdx.x;                 // (i*B + b)*H + h
    int w0 = blockIdx.y * 32;
    int h = ibh % H_;
    int ib = ibh / H_;                    // i*B + b
    int i = ib / B_, b = ib % B_;
    int tx = threadIdx.x, ty = threadIdx.y;
    const float* src = in + ((size_t)((i + 1) * B_ + b) * C_) * HW_ + (size_t)h * W_ + w0;
#pragma unroll
    for (int cs = 0; cs < 32; cs += 8)
        tile[cs + ty][tx] = src[(size_t)(cs + ty) * HW_ + tx];
    __syncthreads();
    __hip_bfloat16* dst = outT + ((size_t)ib * HW_ + (size_t)h * W_ + w0) * C_;
#pragma unroll
    for (int wv = 0; wv < 32; wv += 8)
        dst[(size_t)(wv + ty) * C_ + tx] = __float2bfloat16(tile[tx][wv + ty]);
}

// ---------------------------------------------------------------------------
// K2: LDS-box-staged volume kernel.
// Phase 1 (64 px x 4 views; wave v owns view v): per-pixel projection ->
//   wave-reduce tap bounding box; if it fits 20x8 records, store LOCAL tap
//   offsets + box meta; else store global offsets (fallback flag).
// Staging: per fitting view, load box rows (contiguous 64B records) from L2
//   coalesced into LDS (fixed 20-rec row stride).
// Phase 2 (16w x 4c4 x 4hg): taps via ds_read_b128 from LDS boxes (or global
//   for fallback views); pk_fma accumulate; NT stores + pv wave reduce.
// ---------------------------------------------------------------------------
__global__ __launch_bounds__(256, 3) void vol_box_kernel(
    const __hip_bfloat16* __restrict__ featT, const float* __restrict__ features,
    const float* __restrict__ depth_samples, const float* __restrict__ view_weights,
    const float* __restrict__ w_reg, const float* __restrict__ b_reg,
    const float* __restrict__ projs, float* __restrict__ out_vol,
    float* __restrict__ out_pv) {
    __shared__ float wrow[NSRC][64][12];                     // 12288 B
    __shared__ int4 boxmeta[NSRC];                           // 64 B
    __shared__ __align__(16) char boxes[NSRC][BOXB];         // 40960 B

    int bid = blockIdx.x;
    int lid = (bid & 7) * NB_VOL8 + (bid >> 3);   // bijective XCD chunking
    int d = lid % D_;
    int r = lid / D_;
    int wg = r % (W_ / 16);
    r /= (W_ / 16);
    int h4 = r % (H_ / 4);
    int b = r / (H_ / 4);                          // block-uniform

    int tix = threadIdx.x;

    // ---------------- phase 1 ----------------
    {
        int p = tix & 63;           // pixel slot
        int v = tix >> 6;           // view (== wave id)
        int w = wg * 16 + (p & 15);
        int h = h4 * 4 + (p >> 4);
        int pix = ((b * D_ + d) * H_ + h) * W_ + w;
        float dep = depth_samples[pix];
        float vw = view_weights[((size_t)(b * NSRC + v) * H_ + h) * W_ + w];
        const float* pr = projs + (b * NSRC + v) * 12;
        float xf = (float)w, yf = (float)h;
        float rx = pr[0] * xf + pr[1] * yf + pr[2];
        float ry = pr[3] * xf + pr[4] * yf + pr[5];
        float rz = pr[6] * xf + pr[7] * yf + pr[8];
        float pxn = rx * dep + pr[9];
        float pyn = ry * dep + pr[10];
        float z = rz * dep + pr[11];
        bool valid = z > 0.001f;
        float zr = __builtin_amdgcn_rcpf(valid ? z : 1.f);
        float px = valid ? pxn * zr : -10000.f;
        float py = valid ? pyn * zr : -10000.f;

        float fx = floorf(px), fy = floorf(py);

        // wave-level box reduction (wave == one view: 64 tile pixels)
        float fxmin = fx, fxmax = fx, fymin = fy, fymax = fy;
#pragma unroll
        for (int m = 1; m < 64; m <<= 1) {
            fxmin = fminf(fxmin, __shfl_xor(fxmin, m, 64));
            fxmax = fmaxf(fxmax, __shfl_xor(fxmax, m, 64));
            fymin = fminf(fymin, __shfl_xor(fymin, m, 64));
            fymax = fmaxf(fymax, __shfl_xor(fymax, m, 64));
        }
        int cx0 = min(max((int)fxmin, 0), W_ - 1);
        int cx1 = min(max((int)fxmax + 1, 0), W_ - 1);
        int cy0 = min(max((int)fymin, 0), H_ - 1);
        int cy1 = min(max((int)fymax + 1, 0), H_ - 1);
        int bw = cx1 - cx0 + 1, bh = cy1 - cy0 + 1;
        bool fits = (bw <= CAPX) && (bh <= CAPY);

        float wx1 = px - fx, wx0 = 1.f - wx1;
        float wy1 = py - fy, wy0 = 1.f - wy1;
        bool vx0 = (fx >= 0.f) && (fx <= (float)(W_ - 1));
        bool vx1 = (fx >= -1.f) && (fx <= (float)(W_ - 2));
        bool vy0 = (fy >= 0.f) && (fy <= (float)(H_ - 1));
        bool vy1 = (fy >= -1.f) && (fy <= (float)(H_ - 2));
        int ix0 = min(max((int)fx, 0), W_ - 1);
        int ix1 = min(max((int)fx + 1, 0), W_ - 1);
        int iy0 = min(max((int)fy, 0), H_ - 1);
        int iy1 = min(max((int)fy + 1, 0), H_ - 1);
        float w00 = wx0 * wy0 * ((vx0 && vy0) ? vw : 0.f);
        float w10 = wx1 * wy0 * ((vx1 && vy0) ? vw : 0.f);
        float w01 = wx0 * wy1 * ((vx0 && vy1) ? vw : 0.f);
        float w11 = wx1 * wy1 * ((vx1 && vy1) ? vw : 0.f);

        int o00, o10, o01, o11;
        if (fits) {   // local record offsets, fixed CAPX stride
            o00 = ((iy0 - cy0) * CAPX + (ix0 - cx0)) << 6;
            o10 = ((iy0 - cy0) * CAPX + (ix1 - cx0)) << 6;
            o01 = ((iy1 - cy0) * CAPX + (ix0 - cx0)) << 6;
            o11 = ((iy1 - cy0) * CAPX + (ix1 - cx0)) << 6;
        } else {      // global byte offsets
            o00 = (iy0 * W_ + ix0) << 6;
            o10 = (iy0 * W_ + ix1) << 6;
            o01 = (iy1 * W_ + ix0) << 6;
            o11 = (iy1 * W_ + ix1) << 6;
        }
        float* row = &wrow[v][p][0];
        *(float4*)row = make_float4(w00, w10, w01, w11);
        *(int4*)(row + 4) = make_int4(o00, o10, o01, o11);
        row[8] = vw;
        if (p == 0) boxmeta[v] = make_int4(cx0, cy0, bw, fits ? bh : 0);
    }
    __syncthreads();

    // ---------------- box staging (all 256 threads, per view) ----------------
#pragma unroll
    for (int v = 0; v < NSRC; ++v) {
        int4 mv = boxmeta[v];
        int bh2 = mv.w;
        if (bh2 > 0) {
            int nq = bh2 * (CAPX * 4);    // 16B chunks (full CAPX-wide rows)
            const char* fvb = (const char*)(featT + (size_t)(v * B_ + b) * HW_ * C_);
            for (int q = tix; q < nq; q += 256) {
                int rrow = q / (CAPX * 4);            // const divisor
                int c = q - rrow * (CAPX * 4);
                int col = min(mv.x + (c >> 2), W_ - 1);
                uint4 val = *(const uint4*)(fvb + ((((mv.y + rrow) * W_ + col) << 6) + ((c & 3) << 4)));
                *(uint4*)(&boxes[v][0] + (q << 4)) = val;
            }
        }
    }
    __syncthreads();

    // ---------------- phase 2 ----------------
    int w16 = tix & 15;
    int c4 = (tix >> 4) & 3;
    int hg = tix >> 6;
    int p2 = w16 + 16 * hg;
    int h2 = h4 * 4 + hg;
    int w2 = wg * 16 + w16;
    int c0 = c4 * 8;
    int c16b = c4 * 16;

    // ref feats + w_reg (issue early; independent)
    const float* refp = features + ((size_t)b * C_ + c0) * HW_ + (size_t)h2 * W_ + w2;
    float refv[8];
#pragma unroll
    for (int k = 0; k < 8; ++k) refv[k] = refp[(size_t)k * HW_];
    float4 wr0 = *(const float4*)(w_reg + c0);
    float4 wr1 = *(const float4*)(w_reg + c0 + 4);
    float breg = b_reg[0];

    float wsum = 1e-5f;
    f32x2 acc[4];
#pragma unroll
    for (int j = 0; j < 4; ++j) acc[j] = (f32x2){0.f, 0.f};

#define ACCPK(word, j, wgt)                                              \
    {                                                                    \
        f32x2 tt;                                                        \
        tt.x = __uint_as_float((word) << 16);                            \
        tt.y = __uint_as_float((word) & 0xffff0000u);                    \
        acc[j] += tt * (wgt);                                            \
    }
#define ACCTAP(uu, wcomp)                                                \
    {                                                                    \
        f32x2 wv = (f32x2){wcomp, wcomp};                                \
        ACCPK((uu).x, 0, wv)                                             \
        ACCPK((uu).y, 1, wv)                                             \
        ACCPK((uu).z, 2, wv)                                             \
        ACCPK((uu).w, 3, wv)                                             \
    }

#pragma unroll
    for (int v = 0; v < NSRC; ++v) {
        const float* row = &wrow[v][p2][0];
        float4 wv4 = *(const float4*)row;
        int4 ov = *(const int4*)(row + 4);
        wsum += row[8];
        uint4 u0, u1, u2, u3;
        if (boxmeta[v].w > 0) {
            const char* lb = &boxes[v][0] + c16b;
            u0 = *(const uint4*)(lb + ov.x);
            u1 = *(const uint4*)(lb + ov.y);
            u2 = *(const uint4*)(lb + ov.z);
            u3 = *(const uint4*)(lb + ov.w);
        } else {
            const char* fv = (const char*)(featT + (size_t)(v * B_ + b) * HW_ * C_) + c16b;
            u0 = *(const uint4*)(fv + ov.x);
            u1 = *(const uint4*)(fv + ov.y);
            u2 = *(const uint4*)(fv + ov.z);
            u3 = *(const uint4*)(fv + ov.w);
        }
        ACCTAP(u0, wv4.x)
        ACCTAP(u1, wv4.y)
        ACCTAP(u2, wv4.z)
        ACCTAP(u3, wv4.w)
    }
#undef ACCTAP
#undef ACCPK

    float inv_wsum = __builtin_amdgcn_rcpf(wsum);   // wsum in [0.4, 4.0001]
    int pix_idx = ((b * D_ + d) * H_ + h2) * W_ + w2;
    size_t obase = (size_t)b * C_ * DHW_ + (size_t)d * HW_ + (size_t)h2 * W_ + w2;
    float wrr[8] = {wr0.x, wr0.y, wr0.z, wr0.w, wr1.x, wr1.y, wr1.z, wr1.w};
    float pv = 0.f;
#pragma unroll
    for (int k = 0; k < 8; ++k) {
        float vc = refv[k] * acc[k >> 1][k & 1] * inv_wsum;
        __builtin_nontemporal_store(vc, &out_vol[obase + (size_t)(c0 + k) * DHW_]);
        pv += vc * wrr[k];
    }
    pv += __shfl_xor(pv, 16, 64);
    pv += __shfl_xor(pv, 32, 64);
    if (c4 == 0) out_pv[pix_idx] = pv + breg;
}

// ---------------------------------------------------------------------------
// Fallback: one-thread-per-pixel channel-first f32 kernel (no workspace).
// ---------------------------------------------------------------------------
__global__ __launch_bounds__(256) void vol_fallback_kernel(
    const float* __restrict__ feat, const float* __restrict__ depth_samples,
    const float* __restrict__ view_weights, const float* __restrict__ w_reg,
    const float* __restrict__ b_reg, const float* __restrict__ projs,
    float* __restrict__ out_vol, float* __restrict__ out_pv) {
    int tid = blockIdx.x * 256 + threadIdx.x;
    if (tid >= TOTAL_BDHW) return;
    int w = tid % W_;
    int t2 = tid / W_;
    int h = t2 % H_;
    t2 /= H_;
    int d = t2 % D_;
    int b = t2 / D_;

    float xf = (float)w, yf = (float)h;
    float dep = depth_samples[tid];
    float s[C_];
#pragma unroll
    for (int c = 0; c < C_; ++c) s[c] = 0.f;
    float wsum = 1e-5f;

    for (int i = 0; i < NSRC; ++i) {
        float vw = view_weights[((size_t)(b * NSRC + i) * H_ + h) * W_ + w];
        wsum += vw;
        const float* pr = projs + (b * NSRC + i) * 12;
        float rx = pr[0] * xf + pr[1] * yf + pr[2];
        float ry = pr[3] * xf + pr[4] * yf + pr[5];
        float rz = pr[6] * xf + pr[7] * yf + pr[8];
        float pxn = rx * dep + pr[9];
        float pyn = ry * dep + pr[10];
        float z = rz * dep + pr[11];
        bool valid = z > 0.001f;
        float zs = valid ? z : 1.f;
        float px = valid ? pxn / zs : -10000.f;
        float py = valid ? pyn / zs : -10000.f;
        float x0f = floorf(px), y0f = floorf(py);
        float x1f = x0f + 1.f, y1f = y0f + 1.f;
        float wx1 = px - x0f, wx0 = 1.f - wx1;
        float wy1 = py - y0f, wy0 = 1.f - wy1;
        bool vx0 = (x0f >= 0.f) && (x0f <= (float)(W_ - 1));
        bool vx1 = (x1f >= 0.f) && (x1f <= (float)(W_ - 1));
        bool vy0 = (y0f >= 0.f) && (y0f <= (float)(H_ - 1));
        bool vy1 = (y1f >= 0.f) && (y1f <= (float)(H_ - 1));
        int ix0 = (int)fminf(fmaxf(x0f, 0.f), (float)(W_ - 1));
        int ix1 = (int)fminf(fmaxf(x1f, 0.f), (float)(W_ - 1));
        int iy0 = (int)fminf(fmaxf(y0f, 0.f), (float)(H_ - 1));
        int iy1 = (int)fminf(fmaxf(y1f, 0.f), (float)(H_ - 1));
        float w00 = wx0 * wy0 * ((vx0 && vy0) ? vw : 0.f);
        float w10 = wx1 * wy0 * ((vx1 && vy0) ? vw : 0.f);
        float w01 = wx0 * wy1 * ((vx0 && vy1) ? vw : 0.f);
        float w11 = wx1 * wy1 * ((vx1 && vy1) ? vw : 0.f);
        const float* base = feat + (size_t)((i + 1) * B_ + b) * C_ * HW_;
        const float* q00 = base + (size_t)iy0 * W_ + ix0;
        const float* q10 = base + (size_t)iy0 * W_ + ix1;
        const float* q01 = base + (size_t)iy1 * W_ + ix0;
        const float* q11 = base + (size_t)iy1 * W_ + ix1;
#pragma unroll
        for (int c = 0; c < C_; ++c)
            s[c] += q00[(size_t)c * HW_] * w00 + q10[(size_t)c * HW_] * w10 +
                    q01[(size_t)c * HW_] * w01 + q11[(size_t)c * HW_] * w11;
    }
    float inv_wsum = 1.f / wsum;
    size_t obase = (size_t)b * C_ * DHW_ + (size_t)d * HW_ + (size_t)h * W_ + w;
    const float* refp = feat + (size_t)b * C_ * HW_ + (size_t)h * W_ + w;
    float pv = 0.f;
#pragma unroll
    for (int c = 0; c < C_; ++c) {
        float vc = refp[(size_t)c * HW_] * s[c] * inv_wsum;
        out_vol[obase + (size_t)c * DHW_] = vc;
        pv += vc * w_reg[c];
    }
    out_pv[tid] = pv + b_reg[0];
}

// ---------------------------------------------------------------------------
// K3: softmax over D (in-place on pv = prob slot), depth, vw passthrough.
// ---------------------------------------------------------------------------
__global__ __launch_bounds__(256) void finalize_kernel(
    const float* __restrict__ ds, const float* __restrict__ vw,
    float* __restrict__ out_depth, float* __restrict__ out_vw,
    float* __restrict__ pv) {
    int tid = blockIdx.x * 256 + threadIdx.x;
    if (tid >= BHW_) return;
    int w = tid % W_;
    int t2 = tid / W_;
    int h = t2 % H_;
    int b = t2 / H_;
    size_t base = (size_t)b * DHW_ + (size_t)h * W_ + w;

    float p[D_];
    float m = -1e30f;
#pragma unroll
    for (int d = 0; d < D_; ++d) {
        p[d] = pv[base + (size_t)d * HW_];
        m = fmaxf(m, p[d]);
    }
    float ssum = 0.f;
#pragma unroll
    for (int d = 0; d < D_; ++d) {
        p[d] = expf(p[d] - m);
        ssum += p[d];
    }
    float inv = 1.f / ssum;
    float dep = 0.f;
#pragma unroll
    for (int d = 0; d < D_; ++d) {
        float pr = p[d] * inv;
        pv[base + (size_t)d * HW_] = pr;
        dep += pr * ds[base + (size_t)d * HW_];
    }
    out_depth[tid] = dep;
#pragma unroll
    for (int k = 0; k < NSRC; ++k)
        out_vw[tid + k * BHW_] = vw[tid + k * BHW_];
}

// ---------------------------------------------------------------------------
extern "C" void kernel_launch(void* const* d_in, const int* in_sizes, int n_in,
                              void* d_out, int out_size, void* d_ws, size_t ws_size,
                              hipStream_t stream) {
    const float* features = (const float*)d_in[0];
    const float* pm       = (const float*)d_in[1];
    const float* dsamp    = (const float*)d_in[2];
    const float* vweights = (const float*)d_in[3];
    const float* w_reg    = (const float*)d_in[4];
    const float* b_reg    = (const float*)d_in[5];

    float* out = (float*)d_out;
    float* out_depth = out;                       // (B,H,W)      40960
    float* out_vw    = out + 40960;               // (B,4,H,W)    163840
    float* out_prob  = out + 204800;              // (B,D,H,W)    1966080 (pv staged here)
    float* out_vol   = out + 2170880;             // (B,C,D,H,W)  62914560

    float* wsf   = (float*)d_ws;
    float* projb = wsf;                            // 96 floats
    __hip_bfloat16* featT = (__hip_bfloat16*)(wsf + 128);  // 512B offset

    size_t need = 512 + (size_t)NSRC * B_ * HW_ * C_ * sizeof(__hip_bfloat16);
    bool chlast = (ws_size >= need);

    hipLaunchKernelGGL(proj_kernel, dim3(1), dim3(64), 0, stream, pm, projb);

    if (chlast) {
        hipLaunchKernelGGL(transpose_bf16_kernel, dim3(NSRC * B_ * H_, W_ / 32),
                           dim3(32, 8), 0, stream, features, featT);
        hipLaunchKernelGGL(vol_box_kernel, dim3(NB_VOL), dim3(256), 0, stream,
                           featT, features, dsamp, vweights, w_reg, b_reg, projb,
                           out_vol, out_prob);
    } else {
        hipLaunchKernelGGL(vol_fallback_kernel, dim3((TOTAL_BDHW + 255) / 256),
                           dim3(256), 0, stream, features, dsamp, vweights, w_reg,
                           b_reg, projb, out_vol, out_prob);
    }

    hipLaunchKernelGGL(finalize_kernel, dim3(BHW_ / 256), dim3(256), 0, stream,
                       dsamp, vweights, out_depth, out_vw, out_prob);
}

// Round 11
// 184.589 us; speedup vs baseline: 1.2628x; 1.2628x over previous
//
#include <hip/hip_runtime.h>
#include <hip/hip_bf16.h>
#include <math.h>

// Problem constants
#define V_ 5
#define B_ 2
#define C_ 32
#define D_ 48
#define H_ 128
#define W_ 160
#define NSRC 4
#define HW_ (H_ * W_)
#define DHW_ ((size_t)D_ * H_ * W_)
#define BHW_ (B_ * H_ * W_)             // 40960
#define TOTAL_BDHW (B_ * D_ * H_ * W_)  // 1966080

// vol grid geometry: block = 256 thr, covers 16w x 4h pixels x all 32 ch at one d
#define NB_VOL (B_ * (H_ / 4) * (W_ / 16) * D_)  // 30720
#define NB_VOL8 (NB_VOL / 8)                     // 3840

// ---------------------------------------------------------------------------
// K0: projection setup (8 threads, f64 internally).
// ---------------------------------------------------------------------------
__device__ __forceinline__ void combined_proj(const float* p, double* P) {
    double E[16], K[16];
    for (int i = 0; i < 16; ++i) { E[i] = (double)p[i]; K[i] = (double)p[16 + i]; }
    for (int i = 0; i < 16; ++i) P[i] = E[i];
    for (int r = 0; r < 3; ++r)
        for (int c = 0; c < 4; ++c) {
            double s = 0.0;
            for (int j = 0; j < 3; ++j) s += K[r * 4 + j] * E[j * 4 + c];
            P[r * 4 + c] = s;
        }
}

__device__ void invert4(const double* A, double* out) {
    double M[4][8];
    for (int r = 0; r < 4; ++r)
        for (int c = 0; c < 4; ++c) {
            M[r][c] = A[r * 4 + c];
            M[r][c + 4] = (r == c) ? 1.0 : 0.0;
        }
    for (int col = 0; col < 4; ++col) {
        int piv = col;
        double best = fabs(M[col][col]);
        for (int r = col + 1; r < 4; ++r) {
            double v = fabs(M[r][col]);
            if (v > best) { best = v; piv = r; }
        }
        if (piv != col)
            for (int c = 0; c < 8; ++c) {
                double t = M[col][c]; M[col][c] = M[piv][c]; M[piv][c] = t;
            }
        double s = 1.0 / M[col][col];
        for (int c = 0; c < 8; ++c) M[col][c] *= s;
        for (int r = 0; r < 4; ++r)
            if (r != col) {
                double f = M[r][col];
                if (f != 0.0)
                    for (int c = 0; c < 8; ++c) M[r][c] -= f * M[col][c];
            }
    }
    for (int r = 0; r < 4; ++r)
        for (int c = 0; c < 4; ++c) out[r * 4 + c] = M[r][c + 4];
}

__global__ void proj_kernel(const float* __restrict__ pm, float* __restrict__ out) {
    int t = threadIdx.x;
    if (t >= B_ * NSRC) return;
    int b = t / NSRC, i = t % NSRC;
    double Pref[16], Psrc[16];
    combined_proj(pm + (size_t)((b * V_ + 0) * 2) * 16, Pref);
    combined_proj(pm + (size_t)((b * V_ + (i + 1)) * 2) * 16, Psrc);
    double inv[16];
    invert4(Pref, inv);
    double M[16];
    for (int r = 0; r < 4; ++r)
        for (int c = 0; c < 4; ++c) {
            double s = 0.0;
            for (int j = 0; j < 4; ++j) s += Psrc[r * 4 + j] * inv[j * 4 + c];
            M[r * 4 + c] = s;
        }
    float* o = out + t * 12;
    o[0] = (float)M[0];  o[1] = (float)M[1];  o[2] = (float)M[2];
    o[3] = (float)M[4];  o[4] = (float)M[5];  o[5] = (float)M[6];
    o[6] = (float)M[8];  o[7] = (float)M[9];  o[8] = (float)M[10];
    o[9] = (float)M[3];  o[10] = (float)M[7]; o[11] = (float)M[11];
}

// ---------------------------------------------------------------------------
// K1: transpose + convert src views: (v=1..4, b, c, h, w) f32
//     -> channel-last bf16 (i, b, h, w, c), i = v-1.
// ---------------------------------------------------------------------------
__global__ __launch_bounds__(256) void transpose_bf16_kernel(
    const float* __restrict__ in, __hip_bfloat16* __restrict__ outT) {
    __shared__ float tile[32][33];
    int ibh = blockIdx.x;                 // (i*B + b)*H + h
    int w0 = blockIdx.y * 32;
    int h = ibh % H_;
    int ib = ibh / H_;                    // i*B + b
    int i = ib / B_, b = ib % B_;
    int tx = threadIdx.x, ty = threadIdx.y;
    const float* src = in + ((size_t)((i + 1) * B_ + b) * C_) * HW_ + (size_t)h * W_ + w0;
#pragma unroll
    for (int cs = 0; cs < 32; cs += 8)
        tile[cs + ty][tx] = src[(size_t)(cs + ty) * HW_ + tx];
    __syncthreads();
    __hip_bfloat16* dst = outT + ((size_t)ib * HW_ + (size_t)h * W_ + w0) * C_;
#pragma unroll
    for (int wv = 0; wv < 32; wv += 8)
        dst[(size_t)(wv + ty) * C_ + tx] = __float2bfloat16(tile[tx][wv + ty]);
}

// ---------------------------------------------------------------------------
// K2: two-phase volume kernel (batched gather; PLAIN stores through L2 —
// A/B test vs the NT-store variants that all plateaued at ~195 µs).
// Phase 1: 256 thr = 64 pixels x 4 views -> tap weights + offsets to LDS.
// Phase 2: 256 thr = 16w x 4c4 x 4hg; 16 gathers into registers, accumulate,
// volume stores + pv wave reduce.
// ---------------------------------------------------------------------------
__global__ __launch_bounds__(256, 4) void vol_split_kernel(
    const __hip_bfloat16* __restrict__ featT, const float* __restrict__ features,
    const float* __restrict__ depth_samples, const float* __restrict__ view_weights,
    const float* __restrict__ w_reg, const float* __restrict__ b_reg,
    const float* __restrict__ projs, float* __restrict__ out_vol,
    float* __restrict__ out_pv) {
    __shared__ float lds[NSRC * 64 * 12];   // [v][p][12]: w00..w11, o00..o11, vw, pad3

    int bid = blockIdx.x;
    int lid = (bid & 7) * NB_VOL8 + (bid >> 3);   // bijective XCD chunking
    int d = lid % D_;
    int r = lid / D_;
    int wg = r % (W_ / 16);
    r /= (W_ / 16);
    int h4 = r % (H_ / 4);
    int b = r / (H_ / 4);                          // block-uniform

    int tix = threadIdx.x;

    // ---------------- phase 1 ----------------
    {
        int p = tix & 63;           // pixel slot = w16 + 16*hg
        int v = tix >> 6;           // view
        int w = wg * 16 + (p & 15);
        int h = h4 * 4 + (p >> 4);
        int pix = ((b * D_ + d) * H_ + h) * W_ + w;
        float dep = depth_samples[pix];
        float vw = view_weights[((size_t)(b * NSRC + v) * H_ + h) * W_ + w];
        const float* pr = projs + (b * NSRC + v) * 12;
        float xf = (float)w, yf = (float)h;
        float rx = pr[0] * xf + pr[1] * yf + pr[2];
        float ry = pr[3] * xf + pr[4] * yf + pr[5];
        float rz = pr[6] * xf + pr[7] * yf + pr[8];
        float pxn = rx * dep + pr[9];
        float pyn = ry * dep + pr[10];
        float z = rz * dep + pr[11];
        bool valid = z > 0.001f;
        float zr = __builtin_amdgcn_rcpf(valid ? z : 1.f);
        float px = valid ? pxn * zr : -10000.f;
        float py = valid ? pyn * zr : -10000.f;

        float x0f = floorf(px), y0f = floorf(py);
        float wx1 = px - x0f, wx0 = 1.f - wx1;
        float wy1 = py - y0f, wy0 = 1.f - wy1;
        bool vx0 = (x0f >= 0.f) && (x0f <= (float)(W_ - 1));
        bool vx1 = (x0f >= -1.f) && (x0f <= (float)(W_ - 2));
        bool vy0 = (y0f >= 0.f) && (y0f <= (float)(H_ - 1));
        bool vy1 = (y0f >= -1.f) && (y0f <= (float)(H_ - 2));
        int ix0 = (int)fminf(fmaxf(x0f, 0.f), (float)(W_ - 1));
        int ix1 = (int)fminf(fmaxf(x0f + 1.f, 0.f), (float)(W_ - 1));
        int iy0 = (int)fminf(fmaxf(y0f, 0.f), (float)(H_ - 1));
        int iy1 = (int)fminf(fmaxf(y0f + 1.f, 0.f), (float)(H_ - 1));
        float w00 = wx0 * wy0 * ((vx0 && vy0) ? vw : 0.f);
        float w10 = wx1 * wy0 * ((vx1 && vy0) ? vw : 0.f);
        float w01 = wx0 * wy1 * ((vx0 && vy1) ? vw : 0.f);
        float w11 = wx1 * wy1 * ((vx1 && vy1) ? vw : 0.f);

        // byte offsets into channel-last bf16 image: (iy*W+ix)*C*2 = <<6
        int o00 = (iy0 * W_ + ix0) << 6;
        int o10 = (iy0 * W_ + ix1) << 6;
        int o01 = (iy1 * W_ + ix0) << 6;
        int o11 = (iy1 * W_ + ix1) << 6;

        float* row = lds + (size_t)((v << 6) + p) * 12;
        *(float4*)row = make_float4(w00, w10, w01, w11);
        *(int4*)(row + 4) = make_int4(o00, o10, o01, o11);
        row[8] = vw;
    }
    __syncthreads();

    // ---------------- phase 2 ----------------
    int w16 = tix & 15;
    int c4 = (tix >> 4) & 3;
    int hg = tix >> 6;
    int p = w16 + 16 * hg;
    int h = h4 * 4 + hg;
    int w = wg * 16 + w16;
    int c0 = c4 * 8;
    int c16 = c4 * 16;              // byte offset of this c-quarter

    // Read all 4 LDS rows first.
    float4 wv4[NSRC];
    int4 ov[NSRC];
    float vws[NSRC];
#pragma unroll
    for (int v = 0; v < NSRC; ++v) {
        const float* row = lds + (size_t)((v << 6) + p) * 12;
        wv4[v] = *(const float4*)row;
        ov[v] = *(const int4*)(row + 4);
        vws[v] = row[8];
    }
    float wsum = 1e-5f + vws[0] + vws[1] + vws[2] + vws[3];

    // Issue ALL 16 gathers into registers (static indexing -> stays in VGPRs).
    uint4 u[NSRC][4];
#pragma unroll
    for (int v = 0; v < NSRC; ++v) {
        const char* fv = (const char*)(featT + (size_t)(v * B_ + b) * HW_ * C_) + c16;
        u[v][0] = *(const uint4*)(fv + ov[v].x);
        u[v][1] = *(const uint4*)(fv + ov[v].y);
        u[v][2] = *(const uint4*)(fv + ov[v].z);
        u[v][3] = *(const uint4*)(fv + ov[v].w);
    }

    float s[8];
#pragma unroll
    for (int k = 0; k < 8; ++k) s[k] = 0.f;

#define ACC1(uu, wgt)                                                    \
    {                                                                    \
        s[0] += __uint_as_float((uu).x << 16) * (wgt);                   \
        s[1] += __uint_as_float((uu).x & 0xffff0000u) * (wgt);           \
        s[2] += __uint_as_float((uu).y << 16) * (wgt);                   \
        s[3] += __uint_as_float((uu).y & 0xffff0000u) * (wgt);           \
        s[4] += __uint_as_float((uu).z << 16) * (wgt);                   \
        s[5] += __uint_as_float((uu).z & 0xffff0000u) * (wgt);           \
        s[6] += __uint_as_float((uu).w << 16) * (wgt);                   \
        s[7] += __uint_as_float((uu).w & 0xffff0000u) * (wgt);           \
    }
#pragma unroll
    for (int v = 0; v < NSRC; ++v) {
        ACC1(u[v][0], wv4[v].x)
        ACC1(u[v][1], wv4[v].y)
        ACC1(u[v][2], wv4[v].z)
        ACC1(u[v][3], wv4[v].w)
    }
#undef ACC1

    float inv_wsum = __builtin_amdgcn_rcpf(wsum);
    // wsum in [1e-5+0.4, 1e-5+4]; rcp ~1ulp is fine here
    int pix_idx = ((b * D_ + d) * H_ + h) * W_ + w;
    size_t obase = (size_t)b * C_ * DHW_ + (size_t)d * HW_ + (size_t)h * W_ + w;
    const float* refp = features + ((size_t)b * C_ + c0) * HW_ + (size_t)h * W_ + w;
    float4 wr0 = *(const float4*)(w_reg + c0);
    float4 wr1 = *(const float4*)(w_reg + c0 + 4);
    float wrr[8] = {wr0.x, wr0.y, wr0.z, wr0.w, wr1.x, wr1.y, wr1.z, wr1.w};
    float pv = 0.f;
#pragma unroll
    for (int k = 0; k < 8; ++k) {
        float vc = refp[(size_t)k * HW_] * s[k] * inv_wsum;
        out_vol[obase + (size_t)(c0 + k) * DHW_] = vc;   // plain store (A/B vs NT)
        pv += vc * wrr[k];
    }
    pv += __shfl_xor(pv, 16, 64);
    pv += __shfl_xor(pv, 32, 64);
    if (c4 == 0) out_pv[pix_idx] = pv + b_reg[0];
}

// ---------------------------------------------------------------------------
// Fallback: one-thread-per-pixel channel-first f32 kernel (no workspace).
// ---------------------------------------------------------------------------
__global__ __launch_bounds__(256) void vol_fallback_kernel(
    const float* __restrict__ feat, const float* __restrict__ depth_samples,
    const float* __restrict__ view_weights, const float* __restrict__ w_reg,
    const float* __restrict__ b_reg, const float* __restrict__ projs,
    float* __restrict__ out_vol, float* __restrict__ out_pv) {
    int tid = blockIdx.x * 256 + threadIdx.x;
    if (tid >= TOTAL_BDHW) return;
    int w = tid % W_;
    int t2 = tid / W_;
    int h = t2 % H_;
    t2 /= H_;
    int d = t2 % D_;
    int b = t2 / D_;

    float xf = (float)w, yf = (float)h;
    float dep = depth_samples[tid];
    float s[C_];
#pragma unroll
    for (int c = 0; c < C_; ++c) s[c] = 0.f;
    float wsum = 1e-5f;

    for (int i = 0; i < NSRC; ++i) {
        float vw = view_weights[((size_t)(b * NSRC + i) * H_ + h) * W_ + w];
        wsum += vw;
        const float* pr = projs + (b * NSRC + i) * 12;
        float rx = pr[0] * xf + pr[1] * yf + pr[2];
        float ry = pr[3] * xf + pr[4] * yf + pr[5];
        float rz = pr[6] * xf + pr[7] * yf + pr[8];
        float pxn = rx * dep + pr[9];
        float pyn = ry * dep + pr[10];
        float z = rz * dep + pr[11];
        bool valid = z > 0.001f;
        float zs = valid ? z : 1.f;
        float px = valid ? pxn / zs : -10000.f;
        float py = valid ? pyn / zs : -10000.f;
        float x0f = floorf(px), y0f = floorf(py);
        float x1f = x0f + 1.f, y1f = y0f + 1.f;
        float wx1 = px - x0f, wx0 = 1.f - wx1;
        float wy1 = py - y0f, wy0 = 1.f - wy1;
        bool vx0 = (x0f >= 0.f) && (x0f <= (float)(W_ - 1));
        bool vx1 = (x1f >= 0.f) && (x1f <= (float)(W_ - 1));
        bool vy0 = (y0f >= 0.f) && (y0f <= (float)(H_ - 1));
        bool vy1 = (y1f >= 0.f) && (y1f <= (float)(H_ - 1));
        int ix0 = (int)fminf(fmaxf(x0f, 0.f), (float)(W_ - 1));
        int ix1 = (int)fminf(fmaxf(x1f, 0.f), (float)(W_ - 1));
        int iy0 = (int)fminf(fmaxf(y0f, 0.f), (float)(H_ - 1));
        int iy1 = (int)fminf(fmaxf(y1f, 0.f), (float)(H_ - 1));
        float w00 = wx0 * wy0 * ((vx0 && vy0) ? vw : 0.f);
        float w10 = wx1 * wy0 * ((vx1 && vy0) ? vw : 0.f);
        float w01 = wx0 * wy1 * ((vx0 && vy1) ? vw : 0.f);
        float w11 = wx1 * wy1 * ((vx1 && vy1) ? vw : 0.f);
        const float* base = feat + (size_t)((i + 1) * B_ + b) * C_ * HW_;
        const float* q00 = base + (size_t)iy0 * W_ + ix0;
        const float* q10 = base + (size_t)iy0 * W_ + ix1;
        const float* q01 = base + (size_t)iy1 * W_ + ix0;
        const float* q11 = base + (size_t)iy1 * W_ + ix1;
#pragma unroll
        for (int c = 0; c < C_; ++c)
            s[c] += q00[(size_t)c * HW_] * w00 + q10[(size_t)c * HW_] * w10 +
                    q01[(size_t)c * HW_] * w01 + q11[(size_t)c * HW_] * w11;
    }
    float inv_wsum = 1.f / wsum;
    size_t obase = (size_t)b * C_ * DHW_ + (size_t)d * HW_ + (size_t)h * W_ + w;
    const float* refp = feat + (size_t)b * C_ * HW_ + (size_t)h * W_ + w;
    float pv = 0.f;
#pragma unroll
    for (int c = 0; c < C_; ++c) {
        float vc = refp[(size_t)c * HW_] * s[c] * inv_wsum;
        out_vol[obase + (size_t)c * DHW_] = vc;
        pv += vc * w_reg[c];
    }
    out_pv[tid] = pv + b_reg[0];
}

// ---------------------------------------------------------------------------
// K3: softmax over D (in-place on pv = prob slot), depth, vw passthrough.
// ---------------------------------------------------------------------------
__global__ __launch_bounds__(256) void finalize_kernel(
    const float* __restrict__ ds, const float* __restrict__ vw,
    float* __restrict__ out_depth, float* __restrict__ out_vw,
    float* __restrict__ pv) {
    int tid = blockIdx.x * 256 + threadIdx.x;
    if (tid >= BHW_) return;
    int w = tid % W_;
    int t2 = tid / W_;
    int h = t2 % H_;
    int b = t2 / H_;
    size_t base = (size_t)b * DHW_ + (size_t)h * W_ + w;

    float p[D_];
    float m = -1e30f;
#pragma unroll
    for (int d = 0; d < D_; ++d) {
        p[d] = pv[base + (size_t)d * HW_];
        m = fmaxf(m, p[d]);
    }
    float ssum = 0.f;
#pragma unroll
    for (int d = 0; d < D_; ++d) {
        p[d] = expf(p[d] - m);
        ssum += p[d];
    }
    float inv = 1.f / ssum;
    float dep = 0.f;
#pragma unroll
    for (int d = 0; d < D_; ++d) {
        float pr = p[d] * inv;
        pv[base + (size_t)d * HW_] = pr;
        dep += pr * ds[base + (size_t)d * HW_];
    }
    out_depth[tid] = dep;
#pragma unroll
    for (int k = 0; k < NSRC; ++k)
        out_vw[tid + k * BHW_] = vw[tid + k * BHW_];
}

// ---------------------------------------------------------------------------
extern "C" void kernel_launch(void* const* d_in, const int* in_sizes, int n_in,
                              void* d_out, int out_size, void* d_ws, size_t ws_size,
                              hipStream_t stream) {
    const float* features = (const float*)d_in[0];
    const float* pm       = (const float*)d_in[1];
    const float* dsamp    = (const float*)d_in[2];
    const float* vweights = (const float*)d_in[3];
    const float* w_reg    = (const float*)d_in[4];
    const float* b_reg    = (const float*)d_in[5];

    float* out = (float*)d_out;
    float* out_depth = out;                       // (B,H,W)      40960
    float* out_vw    = out + 40960;               // (B,4,H,W)    163840
    float* out_prob  = out + 204800;              // (B,D,H,W)    1966080 (pv staged here)
    float* out_vol   = out + 2170880;             // (B,C,D,H,W)  62914560

    float* wsf   = (float*)d_ws;
    float* projb = wsf;                            // 96 floats
    __hip_bfloat16* featT = (__hip_bfloat16*)(wsf + 128);  // 512B offset

    size_t need = 512 + (size_t)NSRC * B_ * HW_ * C_ * sizeof(__hip_bfloat16);
    bool chlast = (ws_size >= need);

    hipLaunchKernelGGL(proj_kernel, dim3(1), dim3(64), 0, stream, pm, projb);

    if (chlast) {
        hipLaunchKernelGGL(transpose_bf16_kernel, dim3(NSRC * B_ * H_, W_ / 32),
                           dim3(32, 8), 0, stream, features, featT);
        hipLaunchKernelGGL(vol_split_kernel, dim3(NB_VOL), dim3(256), 0, stream,
                           featT, features, dsamp, vweights, w_reg, b_reg, projb,
                           out_vol, out_prob);
    } else {
        hipLaunchKernelGGL(vol_fallback_kernel, dim3((TOTAL_BDHW + 255) / 256),
                           dim3(256), 0, stream, features, dsamp, vweights, w_reg,
                           b_reg, projb, out_vol, out_prob);
    }

    hipLaunchKernelGGL(finalize_kernel, dim3(BHW_ / 256), dim3(256), 0, stream,
                       dsamp, vweights, out_depth, out_vw, out_prob);
}

// Round 12
// 158.721 us; speedup vs baseline: 1.4686x; 1.1630x over previous
//
#include <hip/hip_runtime.h>
#include <hip/hip_bf16.h>
#include <math.h>

// Problem constants
#define V_ 5
#define B_ 2
#define C_ 32
#define D_ 48
#define H_ 128
#define W_ 160
#define NSRC 4
#define HW_ (H_ * W_)
#define DHW_ ((size_t)D_ * H_ * W_)
#define BHW_ (B_ * H_ * W_)             // 40960
#define TOTAL_BDHW (B_ * D_ * H_ * W_)  // 1966080

// vol grid geometry: block = 256 thr = (16 w) x (4 c-quarters) x (4 h)
// logical block id: d innermost, then wg (W/16=10), then h4 (H/4=32), then b
#define NB_VOL (B_ * (H_ / 4) * (W_ / 16) * D_)  // 30720
#define NB_VOL8 (NB_VOL / 8)                     // 3840

// ---------------------------------------------------------------------------
// K0: projection setup (8 threads, f64 internally).
// ---------------------------------------------------------------------------
__device__ __forceinline__ void combined_proj(const float* p, double* P) {
    double E[16], K[16];
    for (int i = 0; i < 16; ++i) { E[i] = (double)p[i]; K[i] = (double)p[16 + i]; }
    for (int i = 0; i < 16; ++i) P[i] = E[i];
    for (int r = 0; r < 3; ++r)
        for (int c = 0; c < 4; ++c) {
            double s = 0.0;
            for (int j = 0; j < 3; ++j) s += K[r * 4 + j] * E[j * 4 + c];
            P[r * 4 + c] = s;
        }
}

__device__ void invert4(const double* A, double* out) {
    double M[4][8];
    for (int r = 0; r < 4; ++r)
        for (int c = 0; c < 4; ++c) {
            M[r][c] = A[r * 4 + c];
            M[r][c + 4] = (r == c) ? 1.0 : 0.0;
        }
    for (int col = 0; col < 4; ++col) {
        int piv = col;
        double best = fabs(M[col][col]);
        for (int r = col + 1; r < 4; ++r) {
            double v = fabs(M[r][col]);
            if (v > best) { best = v; piv = r; }
        }
        if (piv != col)
            for (int c = 0; c < 8; ++c) {
                double t = M[col][c]; M[col][c] = M[piv][c]; M[piv][c] = t;
            }
        double s = 1.0 / M[col][col];
        for (int c = 0; c < 8; ++c) M[col][c] *= s;
        for (int r = 0; r < 4; ++r)
            if (r != col) {
                double f = M[r][col];
                if (f != 0.0)
                    for (int c = 0; c < 8; ++c) M[r][c] -= f * M[col][c];
            }
    }
    for (int r = 0; r < 4; ++r)
        for (int c = 0; c < 4; ++c) out[r * 4 + c] = M[r][c + 4];
}

__global__ void proj_kernel(const float* __restrict__ pm, float* __restrict__ out) {
    int t = threadIdx.x;
    if (t >= B_ * NSRC) return;
    int b = t / NSRC, i = t % NSRC;
    double Pref[16], Psrc[16];
    combined_proj(pm + (size_t)((b * V_ + 0) * 2) * 16, Pref);
    combined_proj(pm + (size_t)((b * V_ + (i + 1)) * 2) * 16, Psrc);
    double inv[16];
    invert4(Pref, inv);
    double M[16];
    for (int r = 0; r < 4; ++r)
        for (int c = 0; c < 4; ++c) {
            double s = 0.0;
            for (int j = 0; j < 4; ++j) s += Psrc[r * 4 + j] * inv[j * 4 + c];
            M[r * 4 + c] = s;
        }
    float* o = out + t * 12;
    o[0] = (float)M[0];  o[1] = (float)M[1];  o[2] = (float)M[2];
    o[3] = (float)M[4];  o[4] = (float)M[5];  o[5] = (float)M[6];
    o[6] = (float)M[8];  o[7] = (float)M[9];  o[8] = (float)M[10];
    o[9] = (float)M[3];  o[10] = (float)M[7]; o[11] = (float)M[11];
}

// ---------------------------------------------------------------------------
// K1: transpose + convert src views: (v=1..4, b, c, h, w) f32
//     -> channel-last bf16 (i, b, h, w, c), i = v-1.
// ---------------------------------------------------------------------------
__global__ __launch_bounds__(256) void transpose_bf16_kernel(
    const float* __restrict__ in, __hip_bfloat16* __restrict__ outT) {
    __shared__ float tile[32][33];
    int ibh = blockIdx.x;                 // (i*B + b)*H + h
    int w0 = blockIdx.y * 32;
    int h = ibh % H_;
    int ib = ibh / H_;                    // i*B + b
    int i = ib / B_, b = ib % B_;
    int tx = threadIdx.x, ty = threadIdx.y;
    const float* src = in + ((size_t)((i + 1) * B_ + b) * C_) * HW_ + (size_t)h * W_ + w0;
#pragma unroll
    for (int cs = 0; cs < 32; cs += 8)
        tile[cs + ty][tx] = src[(size_t)(cs + ty) * HW_ + tx];
    __syncthreads();
    __hip_bfloat16* dst = outT + ((size_t)ib * HW_ + (size_t)h * W_ + w0) * C_;
#pragma unroll
    for (int wv = 0; wv < 32; wv += 8)
        dst[(size_t)(wv + ty) * C_ + tx] = __float2bfloat16(tile[tx][wv + ty]);
}

// ---------------------------------------------------------------------------
// K2: main volume kernel — the round-3 best kernel (bf16 gathers,
// d-innermost blocks, XCD swizzle, NT stores) with the ONLY change being
// the two IEEE divides replaced by v_rcp_f32 (proven-safe numerics).
// ---------------------------------------------------------------------------
__global__ __launch_bounds__(256) void vol_bf16_kernel(
    const __hip_bfloat16* __restrict__ featT, const float* __restrict__ features,
    const float* __restrict__ depth_samples, const float* __restrict__ view_weights,
    const float* __restrict__ w_reg, const float* __restrict__ b_reg,
    const float* __restrict__ projs, float* __restrict__ out_vol,
    float* __restrict__ out_pv) {
    int bid = blockIdx.x;
    int lid = (bid & 7) * NB_VOL8 + (bid >> 3);   // bijective XCD chunking
    int d = lid % D_;
    int r = lid / D_;
    int wg = r % (W_ / 16);
    r /= (W_ / 16);
    int h4 = r % (H_ / 4);
    int b = r / (H_ / 4);                          // block-uniform -> SGPR

    int tix = threadIdx.x;
    int w16 = tix & 15;
    int c4 = (tix >> 4) & 3;
    int hg = tix >> 6;
    int h = h4 * 4 + hg;
    int w = wg * 16 + w16;
    int c0 = c4 * 8;

    int pix_idx = ((b * D_ + d) * H_ + h) * W_ + w;
    float xf = (float)w, yf = (float)h;
    float dep = depth_samples[pix_idx];

    float s[8];
#pragma unroll
    for (int k = 0; k < 8; ++k) s[k] = 0.f;
    float wsum = 1e-5f;

#pragma unroll
    for (int i = 0; i < NSRC; ++i) {
        float vw = view_weights[((size_t)(b * NSRC + i) * H_ + h) * W_ + w];
        wsum += vw;
        const float* pr = projs + (b * NSRC + i) * 12;   // uniform -> s_load
        float rx = pr[0] * xf + pr[1] * yf + pr[2];
        float ry = pr[3] * xf + pr[4] * yf + pr[5];
        float rz = pr[6] * xf + pr[7] * yf + pr[8];
        float pxn = rx * dep + pr[9];
        float pyn = ry * dep + pr[10];
        float z = rz * dep + pr[11];
        bool valid = z > 0.001f;
        float zr = __builtin_amdgcn_rcpf(valid ? z : 1.f);   // rcp replaces divide
        float px = valid ? pxn * zr : -10000.f;
        float py = valid ? pyn * zr : -10000.f;

        float x0f = floorf(px), y0f = floorf(py);
        float x1f = x0f + 1.f, y1f = y0f + 1.f;
        float wx1 = px - x0f, wx0 = 1.f - wx1;
        float wy1 = py - y0f, wy0 = 1.f - wy1;
        bool vx0 = (x0f >= 0.f) && (x0f <= (float)(W_ - 1));
        bool vx1 = (x1f >= 0.f) && (x1f <= (float)(W_ - 1));
        bool vy0 = (y0f >= 0.f) && (y0f <= (float)(H_ - 1));
        bool vy1 = (y1f >= 0.f) && (y1f <= (float)(H_ - 1));
        int ix0 = (int)fminf(fmaxf(x0f, 0.f), (float)(W_ - 1));
        int ix1 = (int)fminf(fmaxf(x1f, 0.f), (float)(W_ - 1));
        int iy0 = (int)fminf(fmaxf(y0f, 0.f), (float)(H_ - 1));
        int iy1 = (int)fminf(fmaxf(y1f, 0.f), (float)(H_ - 1));
        float w00 = wx0 * wy0 * ((vx0 && vy0) ? vw : 0.f);
        float w10 = wx1 * wy0 * ((vx1 && vy0) ? vw : 0.f);
        float w01 = wx0 * wy1 * ((vx0 && vy1) ? vw : 0.f);
        float w11 = wx1 * wy1 * ((vx1 && vy1) ? vw : 0.f);

        const __hip_bfloat16* base = featT + (size_t)(i * B_ + b) * HW_ * C_ + c0;
        uint4 u00 = *(const uint4*)(base + (size_t)(iy0 * W_ + ix0) * C_);
        uint4 u10 = *(const uint4*)(base + (size_t)(iy0 * W_ + ix1) * C_);
        uint4 u01 = *(const uint4*)(base + (size_t)(iy1 * W_ + ix0) * C_);
        uint4 u11 = *(const uint4*)(base + (size_t)(iy1 * W_ + ix1) * C_);

#define ACC1(u, wgt)                                                     \
        {                                                                \
            s[0] += __uint_as_float((u).x << 16) * (wgt);                \
            s[1] += __uint_as_float((u).x & 0xffff0000u) * (wgt);        \
            s[2] += __uint_as_float((u).y << 16) * (wgt);                \
            s[3] += __uint_as_float((u).y & 0xffff0000u) * (wgt);        \
            s[4] += __uint_as_float((u).z << 16) * (wgt);                \
            s[5] += __uint_as_float((u).z & 0xffff0000u) * (wgt);        \
            s[6] += __uint_as_float((u).w << 16) * (wgt);                \
            s[7] += __uint_as_float((u).w & 0xffff0000u) * (wgt);        \
        }
        ACC1(u00, w00)
        ACC1(u10, w10)
        ACC1(u01, w01)
        ACC1(u11, w11)
#undef ACC1
    }

    float inv_wsum = __builtin_amdgcn_rcpf(wsum);   // wsum in [0.4, 4.0001]
    size_t obase = (size_t)b * C_ * DHW_ + (size_t)d * HW_ + (size_t)h * W_ + w;
    // ref view read in f32 from original channel-first features
    const float* refp = features + ((size_t)b * C_ + c0) * HW_ + (size_t)h * W_ + w;
    float pv = 0.f;
#pragma unroll
    for (int k = 0; k < 8; ++k) {
        float vc = refp[(size_t)k * HW_] * s[k] * inv_wsum;
        __builtin_nontemporal_store(vc, &out_vol[obase + (size_t)(c0 + k) * DHW_]);
        pv += vc * w_reg[c0 + k];
    }
    pv += __shfl_xor(pv, 16, 64);
    pv += __shfl_xor(pv, 32, 64);
    if (c4 == 0) out_pv[pix_idx] = pv + b_reg[0];
}

// ---------------------------------------------------------------------------
// Fallback: one-thread-per-pixel channel-first f32 kernel (no workspace).
// ---------------------------------------------------------------------------
__global__ __launch_bounds__(256) void vol_fallback_kernel(
    const float* __restrict__ feat, const float* __restrict__ depth_samples,
    const float* __restrict__ view_weights, const float* __restrict__ w_reg,
    const float* __restrict__ b_reg, const float* __restrict__ projs,
    float* __restrict__ out_vol, float* __restrict__ out_pv) {
    int tid = blockIdx.x * 256 + threadIdx.x;
    if (tid >= TOTAL_BDHW) return;
    int w = tid % W_;
    int t2 = tid / W_;
    int h = t2 % H_;
    t2 /= H_;
    int d = t2 % D_;
    int b = t2 / D_;

    float xf = (float)w, yf = (float)h;
    float dep = depth_samples[tid];
    float s[C_];
#pragma unroll
    for (int c = 0; c < C_; ++c) s[c] = 0.f;
    float wsum = 1e-5f;

    for (int i = 0; i < NSRC; ++i) {
        float vw = view_weights[((size_t)(b * NSRC + i) * H_ + h) * W_ + w];
        wsum += vw;
        const float* pr = projs + (b * NSRC + i) * 12;
        float rx = pr[0] * xf + pr[1] * yf + pr[2];
        float ry = pr[3] * xf + pr[4] * yf + pr[5];
        float rz = pr[6] * xf + pr[7] * yf + pr[8];
        float pxn = rx * dep + pr[9];
        float pyn = ry * dep + pr[10];
        float z = rz * dep + pr[11];
        bool valid = z > 0.001f;
        float zs = valid ? z : 1.f;
        float px = valid ? pxn / zs : -10000.f;
        float py = valid ? pyn / zs : -10000.f;
        float x0f = floorf(px), y0f = floorf(py);
        float x1f = x0f + 1.f, y1f = y0f + 1.f;
        float wx1 = px - x0f, wx0 = 1.f - wx1;
        float wy1 = py - y0f, wy0 = 1.f - wy1;
        bool vx0 = (x0f >= 0.f) && (x0f <= (float)(W_ - 1));
        bool vx1 = (x1f >= 0.f) && (x1f <= (float)(W_ - 1));
        bool vy0 = (y0f >= 0.f) && (y0f <= (float)(H_ - 1));
        bool vy1 = (y1f >= 0.f) && (y1f <= (float)(H_ - 1));
        int ix0 = (int)fminf(fmaxf(x0f, 0.f), (float)(W_ - 1));
        int ix1 = (int)fminf(fmaxf(x1f, 0.f), (float)(W_ - 1));
        int iy0 = (int)fminf(fmaxf(y0f, 0.f), (float)(H_ - 1));
        int iy1 = (int)fminf(fmaxf(y1f, 0.f), (float)(H_ - 1));
        float w00 = wx0 * wy0 * ((vx0 && vy0) ? vw : 0.f);
        float w10 = wx1 * wy0 * ((vx1 && vy0) ? vw : 0.f);
        float w01 = wx0 * wy1 * ((vx0 && vy1) ? vw : 0.f);
        float w11 = wx1 * wy1 * ((vx1 && vy1) ? vw : 0.f);
        const float* base = feat + (size_t)((i + 1) * B_ + b) * C_ * HW_;
        const float* q00 = base + (size_t)iy0 * W_ + ix0;
        const float* q10 = base + (size_t)iy0 * W_ + ix1;
        const float* q01 = base + (size_t)iy1 * W_ + ix0;
        const float* q11 = base + (size_t)iy1 * W_ + ix1;
#pragma unroll
        for (int c = 0; c < C_; ++c)
            s[c] += q00[(size_t)c * HW_] * w00 + q10[(size_t)c * HW_] * w10 +
                    q01[(size_t)c * HW_] * w01 + q11[(size_t)c * HW_] * w11;
    }
    float inv_wsum = 1.f / wsum;
    size_t obase = (size_t)b * C_ * DHW_ + (size_t)d * HW_ + (size_t)h * W_ + w;
    const float* refp = feat + (size_t)b * C_ * HW_ + (size_t)h * W_ + w;
    float pv = 0.f;
#pragma unroll
    for (int c = 0; c < C_; ++c) {
        float vc = refp[(size_t)c * HW_] * s[c] * inv_wsum;
        out_vol[obase + (size_t)c * DHW_] = vc;
        pv += vc * w_reg[c];
    }
    out_pv[tid] = pv + b_reg[0];
}

// ---------------------------------------------------------------------------
// K3: softmax over D (in-place on pv = prob slot), depth, vw passthrough.
// ---------------------------------------------------------------------------
__global__ __launch_bounds__(256) void finalize_kernel(
    const float* __restrict__ ds, const float* __restrict__ vw,
    float* __restrict__ out_depth, float* __restrict__ out_vw,
    float* __restrict__ pv) {
    int tid = blockIdx.x * 256 + threadIdx.x;
    if (tid >= BHW_) return;
    int w = tid % W_;
    int t2 = tid / W_;
    int h = t2 % H_;
    int b = t2 / H_;
    size_t base = (size_t)b * DHW_ + (size_t)h * W_ + w;

    float p[D_];
    float m = -1e30f;
#pragma unroll
    for (int d = 0; d < D_; ++d) {
        p[d] = pv[base + (size_t)d * HW_];
        m = fmaxf(m, p[d]);
    }
    float ssum = 0.f;
#pragma unroll
    for (int d = 0; d < D_; ++d) {
        p[d] = expf(p[d] - m);
        ssum += p[d];
    }
    float inv = 1.f / ssum;
    float dep = 0.f;
#pragma unroll
    for (int d = 0; d < D_; ++d) {
        float pr = p[d] * inv;
        pv[base + (size_t)d * HW_] = pr;
        dep += pr * ds[base + (size_t)d * HW_];
    }
    out_depth[tid] = dep;
#pragma unroll
    for (int k = 0; k < NSRC; ++k)
        out_vw[tid + k * BHW_] = vw[tid + k * BHW_];
}

// ---------------------------------------------------------------------------
extern "C" void kernel_launch(void* const* d_in, const int* in_sizes, int n_in,
                              void* d_out, int out_size, void* d_ws, size_t ws_size,
                              hipStream_t stream) {
    const float* features = (const float*)d_in[0];
    const float* pm       = (const float*)d_in[1];
    const float* dsamp    = (const float*)d_in[2];
    const float* vweights = (const float*)d_in[3];
    const float* w_reg    = (const float*)d_in[4];
    const float* b_reg    = (const float*)d_in[5];

    float* out = (float*)d_out;
    float* out_depth = out;                       // (B,H,W)      40960
    float* out_vw    = out + 40960;               // (B,4,H,W)    163840
    float* out_prob  = out + 204800;              // (B,D,H,W)    1966080 (pv staged here)
    float* out_vol   = out + 2170880;             // (B,C,D,H,W)  62914560

    float* wsf   = (float*)d_ws;
    float* projb = wsf;                            // 96 floats
    __hip_bfloat16* featT = (__hip_bfloat16*)(wsf + 128);  // 512B offset

    size_t need = 512 + (size_t)NSRC * B_ * HW_ * C_ * sizeof(__hip_bfloat16);
    bool chlast = (ws_size >= need);

    hipLaunchKernelGGL(proj_kernel, dim3(1), dim3(64), 0, stream, pm, projb);

    if (chlast) {
        hipLaunchKernelGGL(transpose_bf16_kernel, dim3(NSRC * B_ * H_, W_ / 32),
                           dim3(32, 8), 0, stream, features, featT);
        hipLaunchKernelGGL(vol_bf16_kernel, dim3(NB_VOL), dim3(256), 0, stream,
                           featT, features, dsamp, vweights, w_reg, b_reg, projb,
                           out_vol, out_prob);
    } else {
        hipLaunchKernelGGL(vol_fallback_kernel, dim3((TOTAL_BDHW + 255) / 256),
                           dim3(256), 0, stream, features, dsamp, vweights, w_reg,
                           b_reg, projb, out_vol, out_prob);
    }

    hipLaunchKernelGGL(finalize_kernel, dim3(BHW_ / 256), dim3(256), 0, stream,
                       dsamp, vweights, out_depth, out_vw, out_prob);
}